// Round 4
// baseline (1110.772 us; speedup 1.0000x reference)
//
#include <hip/hip_runtime.h>
#include <hip/hip_bf16.h>
#include <math.h>

// ---------------- problem constants ----------------
#define N_TOK 8192          // B*T
#define C_DIM 768
#define E_NUM 8
#define H_DIM 3072
#define NROWS (N_TOK * 2)   // token-expert pairs = 16384
#define MAXT1 72            // row tiles of 256: 16384/256 + 8
#define NBLK  64            // routing blocks (NROWS/256)
#define KSPLIT 2
#define KCHUNK (H_DIM / KSPLIT)   // 1536
#define NT1 (C_DIM / 64)          // 12 K-tiles gemm1
#define NT2 (KCHUNK / 64)         // 24 K-tiles gemm2
#define NJ1 (H_DIM / 256)         // 12 col tiles gemm1
#define NWG1 (MAXT1 * NJ1)        // 864 = 8 XCDs * 108
#define NWG2 (MAXT1 * 3 * KSPLIT) // 432 = 8 XCDs * 54

typedef unsigned short u16;
typedef __attribute__((ext_vector_type(8))) short   short8;
typedef __attribute__((ext_vector_type(8))) __bf16  bf16x8;
typedef __attribute__((ext_vector_type(4))) float   f32x4;

__device__ __forceinline__ u16 f2bf(float f) {
    __hip_bfloat16 b = __float2bfloat16(f);
    return __builtin_bit_cast(u16, b);
}
__device__ __forceinline__ float bf2f(u16 u) {
    unsigned int v = ((unsigned int)u) << 16;
    return __builtin_bit_cast(float, v);
}

// tanh-form gelu (~3e-4 max dev vs exact, invisible under bf16 noise)
__device__ __forceinline__ float gelu_fast(float x) {
    float x2 = x * x;
    float u  = x * (0.7978845608f + 0.0356774081f * x2);
    float e  = __builtin_amdgcn_exp2f(u * 2.885390082f);     // e^(2u)
    float t  = 1.f - 2.f * __builtin_amdgcn_rcpf(e + 1.f);   // tanh(u)
    return 0.5f * x * (1.f + t);
}

// async global->LDS DMA, 16B per lane; LDS dest is wave-uniform base + lane*16
__device__ __forceinline__ void async_copy16(void* lds, const void* g) {
    __builtin_amdgcn_global_load_lds(
        (const __attribute__((address_space(1))) void*)g,
        (__attribute__((address_space(3))) void*)lds, 16, 0, 0);
}

// ---------------- gating + x cast fused: 1 wave per token ----------------
__global__ void gating_kernel(const float* __restrict__ x, const float* __restrict__ gw,
                              const float* __restrict__ gb,
                              int* __restrict__ topk_idx, float* __restrict__ topk_prob,
                              u16* __restrict__ xb) {
    int token = blockIdx.x;
    int lane  = threadIdx.x;
    const float* xr = x + (size_t)token * C_DIM;
    u16* xbr = xb + (size_t)token * C_DIM;
    float acc[E_NUM];
#pragma unroll
    for (int e = 0; e < E_NUM; ++e) acc[e] = 0.f;
    for (int c = lane; c < C_DIM; c += 64) {
        float xv = xr[c];
        xbr[c] = f2bf(xv);
#pragma unroll
        for (int e = 0; e < E_NUM; ++e) acc[e] += xv * gw[c * E_NUM + e];
    }
#pragma unroll
    for (int e = 0; e < E_NUM; ++e) {
        float v = acc[e];
        for (int off = 32; off > 0; off >>= 1) v += __shfl_down(v, off);
        acc[e] = v;
    }
    if (lane == 0) {
        float l[E_NUM];
#pragma unroll
        for (int e = 0; e < E_NUM; ++e) l[e] = acc[e] + gb[e];
        int e0 = 0;
#pragma unroll
        for (int e = 1; e < E_NUM; ++e) if (l[e] > l[e0]) e0 = e;   // first-index ties like lax.top_k
        int e1 = -1;
#pragma unroll
        for (int e = 0; e < E_NUM; ++e) if (e != e0 && (e1 < 0 || l[e] > l[e1])) e1 = e;
        float p0 = 1.f / (1.f + expf(l[e1] - l[e0]));
        topk_idx[token * 2]      = e0;
        topk_idx[token * 2 + 1]  = e1;
        topk_prob[token * 2]     = p0;
        topk_prob[token * 2 + 1] = 1.f - p0;
    }
}

// ---------------- routing: ballot histogram -> scan -> rank scatter ----------------
__global__ void hist_kernel(const int* __restrict__ topk_idx, int* __restrict__ block_hist) {
    __shared__ int cnt[E_NUM];
    int tid = threadIdx.x;
    if (tid < E_NUM) cnt[tid] = 0;
    __syncthreads();
    int e = topk_idx[blockIdx.x * 256 + tid];
    int lane = tid & 63;
#pragma unroll
    for (int E = 0; E < E_NUM; ++E) {
        unsigned long long m = __ballot(e == E);
        if (lane == 0) atomicAdd(&cnt[E], __popcll(m));   // LDS atomic, 4 waves only
    }
    __syncthreads();
    if (tid < E_NUM) block_hist[blockIdx.x * E_NUM + tid] = cnt[tid];
}

__global__ void scan_tables_kernel(const int* __restrict__ block_hist,
                                   int* __restrict__ t1_e, int* __restrict__ t1_rs, int* __restrict__ t1_rows,
                                   int* __restrict__ block_base) {
    if (threadIdx.x || blockIdx.x) return;
    int counts[E_NUM], offsets[E_NUM];
    for (int e = 0; e < E_NUM; ++e) {
        int s = 0;
        for (int b = 0; b < NBLK; ++b) s += block_hist[b * E_NUM + e];
        counts[e] = s;
    }
    int off = 0;
    for (int e = 0; e < E_NUM; ++e) { offsets[e] = off; off += counts[e]; }
    for (int e = 0; e < E_NUM; ++e) {
        int s = offsets[e];
        for (int b = 0; b < NBLK; ++b) { block_base[b * E_NUM + e] = s; s += block_hist[b * E_NUM + e]; }
    }
    int t = 0;
    for (int e = 0; e < E_NUM; ++e)
        for (int j = 0; j < counts[e]; j += 256) {
            t1_e[t] = e; t1_rs[t] = offsets[e] + j;
            t1_rows[t] = (counts[e] - j < 256) ? (counts[e] - j) : 256;
            ++t;
        }
    for (; t < MAXT1; ++t) { t1_e[t] = 0; t1_rs[t] = 0; t1_rows[t] = 0; }
}

__global__ void scatter_kernel(const int* __restrict__ topk_idx, const float* __restrict__ topk_prob,
                               const int* __restrict__ block_base,
                               int* __restrict__ row_token, float* __restrict__ row_prob,
                               int* __restrict__ tok2row) {
    __shared__ int wcount[4][E_NUM];
    __shared__ int wbase[4][E_NUM];
    int tid = threadIdx.x, lane = tid & 63, wave = tid >> 6;
    int idx = blockIdx.x * 256 + tid;
    int e = topk_idx[idx];
    float p = topk_prob[idx];
    int rank = 0;
    unsigned long long lt = (1ull << lane) - 1ull;
#pragma unroll
    for (int E = 0; E < E_NUM; ++E) {
        unsigned long long m = __ballot(e == E);
        if (lane == 0) wcount[wave][E] = __popcll(m);
        if (e == E) rank = __popcll(m & lt);
    }
    __syncthreads();
    if (tid < E_NUM) {
        int s = 0;
#pragma unroll
        for (int w = 0; w < 4; ++w) { wbase[w][tid] = s; s += wcount[w][tid]; }
    }
    __syncthreads();
    int pos = block_base[blockIdx.x * E_NUM + e] + wbase[wave][e] + rank;
    row_token[pos] = idx >> 1;
    row_prob[pos]  = p;
    tok2row[idx]   = pos;
}

// in: [E][R][C] fp32 -> out: [E][C][R] bf16.  64x64 tile, 256 threads.
__global__ void transpose_cast_kernel(const float* __restrict__ in, u16* __restrict__ out,
                                      int R, int C) {
    __shared__ float tile[64][65];
    size_t mat = (size_t)R * C;
    const float* src = in + blockIdx.z * mat;
    u16* dst = out + blockIdx.z * mat;
    int c0 = blockIdx.x * 64, r0 = blockIdx.y * 64;
    int tx = threadIdx.x & 15, ty = threadIdx.x >> 4;   // 16 x 16
#pragma unroll
    for (int k = 0; k < 4; ++k) {
        float4 v = *(const float4*)(src + (size_t)(r0 + ty + 16 * k) * C + c0 + tx * 4);
        tile[ty + 16 * k][tx * 4 + 0] = v.x;
        tile[ty + 16 * k][tx * 4 + 1] = v.y;
        tile[ty + 16 * k][tx * 4 + 2] = v.z;
        tile[ty + 16 * k][tx * 4 + 3] = v.w;
    }
    __syncthreads();
#pragma unroll
    for (int k = 0; k < 4; ++k) {
        int c = ty + 16 * k;
        u16 p[4];
#pragma unroll
        for (int j = 0; j < 4; ++j) p[j] = f2bf(tile[tx * 4 + j][c]);
        *(unsigned long long*)(dst + (size_t)(c0 + c) * R + r0 + tx * 4) =
            *(unsigned long long*)p;
    }
}

// ============ GEMM cores: 256x256 tile, BK=64, 8 waves (2Mx4N, 128x64/wave) ============
// Geometry/indexing = R1 (hardware-validated correct). Schedule = m201-style
// 4 phases per K-tile, each {ds_read batch; [stage]; BAR; lgkm0; sched0; 16 MFMA; BAR}:
//   P0: 8 B-frag reads + 4 A-frag reads; STAGE both A halves of tile t+1
//   P1: 4 A reads;                      STAGE both B halves of tile t+1
//   P2: 4 A reads
//   P3: 4 A reads; VMCNT(0) before closing BAR   <- forces stages issued at
//       P0/P1 of THIS tile = 2.5-3.5 phases of latency cover (the R0/R3
//       structures forced stages <=1 phase old -> exposed latency each step).
// All fragment reads are inline-asm ds_read_b128 (R3-proven: stops the compiler
// waitcnt pass from pinning vmcnt(0) to them); rule-#18 lgkm0+sched_barrier(0)
// before each MFMA cluster. Region-overwrite safety: stages into buf b at tile
// t+1's P0/P1 target regions last ds_read at tile t-1's P3, separated by BARs.
// LDS 128KB -> 1 block/CU, 8 waves (m201-proven sufficient for 62% MfmaUtil).

#define SP1 __builtin_amdgcn_s_setprio(1)
#define SP0 __builtin_amdgcn_s_setprio(0)
#define BAR() __builtin_amdgcn_s_barrier()
#define SCB0 __builtin_amdgcn_sched_barrier(0)
#define VMCNT0 asm volatile("s_waitcnt vmcnt(0)" ::: "memory")
#define LGKM0 asm volatile("s_waitcnt lgkmcnt(0)" ::: "memory")

#define DSR(dst, addr, OFF) \
    asm volatile("ds_read_b128 %0, %1 offset:" #OFF : "=v"(dst) : "v"(addr))

#define STAGE_A(BUF, s) do { \
    async_copy16(&As[BUF][0][(size_t)tid * 8],         abase + a_off[0][0] + (unsigned)(s) * 64); \
    async_copy16(&As[BUF][0][(size_t)(512 + tid) * 8], abase + a_off[0][1] + (unsigned)(s) * 64); \
    async_copy16(&As[BUF][1][(size_t)tid * 8],         abase + a_off[1][0] + (unsigned)(s) * 64); \
    async_copy16(&As[BUF][1][(size_t)(512 + tid) * 8], abase + a_off[1][1] + (unsigned)(s) * 64); } while (0)

#define STAGE_B(BUF, s) do { \
    async_copy16(&Bs[BUF][0][(size_t)tid * 8],         bbase + b_off[0][0] + (unsigned)(s) * 64); \
    async_copy16(&Bs[BUF][0][(size_t)(512 + tid) * 8], bbase + b_off[0][1] + (unsigned)(s) * 64); \
    async_copy16(&Bs[BUF][1][(size_t)tid * 8],         bbase + b_off[1][0] + (unsigned)(s) * 64); \
    async_copy16(&Bs[BUF][1][(size_t)(512 + tid) * 8], bbase + b_off[1][1] + (unsigned)(s) * 64); } while (0)

#define MFMA_(d, a, b) \
    d = __builtin_amdgcn_mfma_f32_16x16x32_bf16( \
        __builtin_bit_cast(bf16x8, a), __builtin_bit_cast(bf16x8, b), d, 0, 0, 0)

// one phase's MFMA cluster: rows mi=MI,MI+1 x all ni x both k-halves (16 MFMA)
#define MFQ(MI) \
    _Pragma("unroll") for (int ni = 0; ni < 4; ++ni) { \
        MFMA_(acc[MI][ni],     af[0], bfr[ni][0]); \
        MFMA_(acc[MI][ni],     af[1], bfr[ni][1]); \
        MFMA_(acc[(MI)+1][ni], af[2], bfr[ni][0]); \
        MFMA_(acc[(MI)+1][ni], af[3], bfr[ni][1]); }

#define RD_A4(PK0, PK1, O0, O1) \
    DSR(af[0], PK0, O0); DSR(af[1], PK1, O0); DSR(af[2], PK0, O1); DSR(af[3], PK1, O1)

#define KTILE(PAK0, PAK1, PBK0, PBK1, S0, S1, VM) do { \
    f32x4 af[4]; f32x4 bfr[4][2]; \
    /* P0 */ \
    DSR(bfr[0][0], PBK0, 0);    DSR(bfr[0][1], PBK1, 0); \
    DSR(bfr[1][0], PBK0, 2048); DSR(bfr[1][1], PBK1, 2048); \
    DSR(bfr[2][0], PBK0, 4096); DSR(bfr[2][1], PBK1, 4096); \
    DSR(bfr[3][0], PBK0, 6144); DSR(bfr[3][1], PBK1, 6144); \
    RD_A4(PAK0, PAK1, 0, 2048); \
    S0; \
    BAR(); LGKM0; SCB0; SP1; MFQ(0); SP0; BAR(); \
    /* P1 */ \
    RD_A4(PAK0, PAK1, 4096, 6144); \
    S1; \
    BAR(); LGKM0; SCB0; SP1; MFQ(2); SP0; BAR(); \
    /* P2 */ \
    RD_A4(PAK0, PAK1, 8192, 10240); \
    BAR(); LGKM0; SCB0; SP1; MFQ(4); SP0; BAR(); \
    /* P3 */ \
    RD_A4(PAK0, PAK1, 12288, 14336); \
    VM; \
    BAR(); LGKM0; SCB0; SP1; MFQ(6); SP0; BAR(); \
} while (0)

#define NOSTAGE do {} while (0)

// ---------------- GEMM1: h[r,:] = row_prob[r] * gelu(Xg[r,:] @ W1[e] + b1[e]) ----------------
__global__ __launch_bounds__(512, 2) void gemm1_kernel(
    const u16* __restrict__ xb,     // [N_TOK][C]
    const u16* __restrict__ w1t,    // [E][H][C]
    const float* __restrict__ b1,   // [E][H]
    const int* __restrict__ tile_e, const int* __restrict__ tile_rs,
    const int* __restrict__ tile_nrows,
    const int* __restrict__ row_token, const float* __restrict__ row_prob,
    u16* __restrict__ hout)         // [NROWS][H]
{
    // bijective XCD swizzle (R1-validated): bt fast within XCD -> B tile L2 reuse
    const int l = blockIdx.x;
    const int wg = (l & 7) * (NWG1 >> 3) + (l >> 3);
    const int bt = wg % MAXT1;
    const int jn = wg / MAXT1;            // [0, 12)

    const int rows = tile_nrows[bt];
    if (rows == 0) return;
    const int e = tile_e[bt];
    const int row_start = tile_rs[bt];
    const int n0 = jn * 256;

    __shared__ __align__(16) u16 As[2][2][8192];   // [buf][half][128*64]  64 KB
    __shared__ __align__(16) u16 Bs[2][2][8192];   //                      64 KB

    const int tid = threadIdx.x;
    const int lane = tid & 63;
    const int wave = tid >> 6;
    const int wm = wave >> 2;             // 0..1 (M waves, 128 rows each)
    const int wn = wave & 3;              // 0..3 (N waves, 64 cols each)
    const int m_in = lane & 15, quad = lane >> 4;

    // fragment LDS byte addresses (R1-validated layout/swizzle)
    const unsigned aB = (unsigned)(size_t)&As[0][0][0];
    const unsigned bB = (unsigned)(size_t)&Bs[0][0][0];
    const unsigned swz0 = ((quad)     ^ (m_in & 7)) * 16;
    const unsigned swz1 = ((4 + quad) ^ (m_in & 7)) * 16;
    const unsigned paBase = aB + wm * 16384 + m_in * 128;
    const unsigned pbBase = bB + (wn >> 1) * 16384 + (wn & 1) * 8192 + m_in * 128;
    const unsigned pa00 = paBase + swz0, pa01 = paBase + swz1;
    const unsigned pa10 = pa00 + 32768, pa11 = pa01 + 32768;
    const unsigned pb00 = pbBase + swz0, pb01 = pbBase + swz1;
    const unsigned pb10 = pb00 + 32768, pb11 = pb01 + 32768;

    // stage source offsets (R1-validated pre-swizzle)
    const u16* abase = xb;
    const u16* bbase = w1t;
    unsigned a_off[2][2], b_off[2][2];
#pragma unroll
    for (int hh = 0; hh < 2; ++hh)
#pragma unroll
        for (int it = 0; it < 2; ++it) {
            int u = it * 512 + tid;                  // 0..1023 = 128 rows x 8 units
            int r = u >> 3;
            int cu = (u & 7) ^ (r & 7);              // swizzled source 16B unit
            int grow = hh * 128 + r;
            int tok = row_token[row_start + ((grow < rows) ? grow : 0)];
            a_off[hh][it] = (unsigned)tok * C_DIM + cu * 8;
            b_off[hh][it] = (unsigned)(e * H_DIM + n0 + hh * 128 + r) * C_DIM + cu * 8;
        }

    f32x4 acc[8][4];
#pragma unroll
    for (int i = 0; i < 8; ++i)
#pragma unroll
        for (int j = 0; j < 4; ++j) acc[i][j] = (f32x4){0.f, 0.f, 0.f, 0.f};

    // prologue: tile 0 into buf0
    STAGE_A(0, 0);
    STAGE_B(0, 0);
    VMCNT0;
    BAR();
#pragma unroll 1
    for (int t = 0; t < NT1; t += 2) {
        const bool m2 = (t + 2 < NT1);
        KTILE(pa00, pa01, pb00, pb01,
              STAGE_A(1, t + 1), STAGE_B(1, t + 1), VMCNT0);
        if (m2) {
            KTILE(pa10, pa11, pb10, pb11,
                  STAGE_A(0, t + 2), STAGE_B(0, t + 2), VMCNT0);
        } else {
            KTILE(pa10, pa11, pb10, pb11, NOSTAGE, NOSTAGE, NOSTAGE);
        }
    }

    const float* b1e = b1 + e * H_DIM + n0 + wn * 64;
#pragma unroll
    for (int mi = 0; mi < 8; ++mi) {
#pragma unroll
        for (int r = 0; r < 4; ++r) {
            int lrow = wm * 128 + mi * 16 + quad * 4 + r;
            if (lrow < rows) {
                int grow = row_start + lrow;
                float p = row_prob[grow];
                u16* orow = hout + (size_t)grow * H_DIM + n0 + wn * 64;
#pragma unroll
                for (int ni = 0; ni < 4; ++ni) {
                    int lcol = ni * 16 + m_in;
                    float v = acc[mi][ni][r] + b1e[lcol];
                    orow[lcol] = f2bf(gelu_fast(v) * p);
                }
            }
        }
    }
}

// ---------------- GEMM2: 256x256 tile, split-K=2, bf16 partials ----------------
__global__ __launch_bounds__(512, 2) void gemm2_kernel(
    const u16* __restrict__ hin,    // [NROWS][H]
    const u16* __restrict__ w2t,    // [E][C][H]
    const int* __restrict__ tile_e, const int* __restrict__ tile_rs,
    const int* __restrict__ tile_nrows,
    u16* __restrict__ eo)           // [KSPLIT][NROWS][C] bf16 partials
{
    // bijective XCD swizzle (R1-validated)
    const int l = blockIdx.x;
    const int wg = (l & 7) * (NWG2 >> 3) + (l >> 3);
    const int bt = wg % MAXT1;
    const int combo = wg / MAXT1;         // [0, 6)
    const int jn = combo >> 1;            // [0, 3)
    const int kz = combo & 1;

    const int rows = tile_nrows[bt];
    if (rows == 0) return;
    const int e = tile_e[bt];
    const int row_start = tile_rs[bt];
    const int n0 = jn * 256;

    __shared__ __align__(16) u16 As[2][2][8192];
    __shared__ __align__(16) u16 Bs[2][2][8192];

    const int tid = threadIdx.x;
    const int lane = tid & 63;
    const int wave = tid >> 6;
    const int wm = wave >> 2;
    const int wn = wave & 3;
    const int m_in = lane & 15, quad = lane >> 4;

    const unsigned aB = (unsigned)(size_t)&As[0][0][0];
    const unsigned bB = (unsigned)(size_t)&Bs[0][0][0];
    const unsigned swz0 = ((quad)     ^ (m_in & 7)) * 16;
    const unsigned swz1 = ((4 + quad) ^ (m_in & 7)) * 16;
    const unsigned paBase = aB + wm * 16384 + m_in * 128;
    const unsigned pbBase = bB + (wn >> 1) * 16384 + (wn & 1) * 8192 + m_in * 128;
    const unsigned pa00 = paBase + swz0, pa01 = paBase + swz1;
    const unsigned pa10 = pa00 + 32768, pa11 = pa01 + 32768;
    const unsigned pb00 = pbBase + swz0, pb01 = pbBase + swz1;
    const unsigned pb10 = pb00 + 32768, pb11 = pb01 + 32768;

    const u16* abase = hin;
    const u16* bbase = w2t;
    unsigned a_off[2][2], b_off[2][2];
#pragma unroll
    for (int hh = 0; hh < 2; ++hh)
#pragma unroll
        for (int it = 0; it < 2; ++it) {
            int u = it * 512 + tid;
            int r = u >> 3;
            int cu = (u & 7) ^ (r & 7);
            int grow = hh * 128 + r;
            int ar = (grow < rows) ? grow : 0;
            a_off[hh][it] = (unsigned)(row_start + ar) * H_DIM + kz * KCHUNK + cu * 8;
            b_off[hh][it] = (unsigned)(e * C_DIM + n0 + hh * 128 + r) * H_DIM + kz * KCHUNK + cu * 8;
        }

    f32x4 acc[8][4];
#pragma unroll
    for (int i = 0; i < 8; ++i)
#pragma unroll
        for (int j = 0; j < 4; ++j) acc[i][j] = (f32x4){0.f, 0.f, 0.f, 0.f};

    STAGE_A(0, 0);
    STAGE_B(0, 0);
    VMCNT0;
    BAR();
#pragma unroll 1
    for (int t = 0; t < NT2; t += 2) {
        const bool m2 = (t + 2 < NT2);
        KTILE(pa00, pa01, pb00, pb01,
              STAGE_A(1, t + 1), STAGE_B(1, t + 1), VMCNT0);
        if (m2) {
            KTILE(pa10, pa11, pb10, pb11,
                  STAGE_A(0, t + 2), STAGE_B(0, t + 2), VMCNT0);
        } else {
            KTILE(pa10, pa11, pb10, pb11, NOSTAGE, NOSTAGE, NOSTAGE);
        }
    }

    u16* eop = eo + (size_t)kz * NROWS * C_DIM;
#pragma unroll
    for (int mi = 0; mi < 8; ++mi) {
#pragma unroll
        for (int r = 0; r < 4; ++r) {
            int lrow = wm * 128 + mi * 16 + quad * 4 + r;
            if (lrow < rows) {
                u16* orow = eop + (size_t)(row_start + lrow) * C_DIM + n0 + wn * 64;
#pragma unroll
                for (int ni = 0; ni < 4; ++ni)
                    orow[ni * 16 + m_in] = f2bf(acc[mi][ni][r]);
            }
        }
    }
}

// ---------------- combine: out[t] = sum of 4 partial rows + weighted biases ----------------
__global__ void combine_kernel(const u16* __restrict__ eo, const int* __restrict__ tok2row,
                               const int* __restrict__ topk_idx, const float* __restrict__ topk_prob,
                               const float* __restrict__ b2, float* __restrict__ out) {
    int t = blockIdx.x;
    int c = threadIdx.x * 4;                      // 192 threads x 4 floats = 768
    int r0 = tok2row[t * 2], r1 = tok2row[t * 2 + 1];
    int e0 = topk_idx[t * 2], e1 = topk_idx[t * 2 + 1];
    float p0 = topk_prob[t * 2], p1 = topk_prob[t * 2 + 1];
    const u16* a0 = eo + (size_t)r0 * C_DIM + c;
    const u16* a1 = eo + (size_t)NROWS * C_DIM + (size_t)r0 * C_DIM + c;
    const u16* b0 = eo + (size_t)r1 * C_DIM + c;
    const u16* b1 = eo + (size_t)NROWS * C_DIM + (size_t)r1 * C_DIM + c;
    ushort4 va0 = *(const ushort4*)a0, va1 = *(const ushort4*)a1;
    ushort4 vb0 = *(const ushort4*)b0, vb1 = *(const ushort4*)b1;
    float4 g0 = *(const float4*)(b2 + e0 * C_DIM + c);
    float4 g1 = *(const float4*)(b2 + e1 * C_DIM + c);
    float4 o;
    o.x = bf2f(va0.x) + bf2f(va1.x) + bf2f(vb0.x) + bf2f(vb1.x) + p0 * g0.x + p1 * g1.x;
    o.y = bf2f(va0.y) + bf2f(va1.y) + bf2f(vb0.y) + bf2f(vb1.y) + p0 * g0.y + p1 * g1.y;
    o.z = bf2f(va0.z) + bf2f(va1.z) + bf2f(vb0.z) + bf2f(vb1.z) + p0 * g0.z + p1 * g1.z;
    o.w = bf2f(va0.w) + bf2f(va1.w) + bf2f(vb0.w) + bf2f(vb1.w) + p0 * g0.w + p1 * g1.w;
    *(float4*)(out + (size_t)t * C_DIM + c) = o;
}

// ---------------- launch ----------------
extern "C" void kernel_launch(void* const* d_in, const int* in_sizes, int n_in,
                              void* d_out, int out_size, void* d_ws, size_t ws_size,
                              hipStream_t stream) {
    const float* x      = (const float*)d_in[0];
    const float* gate_w = (const float*)d_in[1];
    const float* gate_b = (const float*)d_in[2];
    const float* w1     = (const float*)d_in[3];
    const float* b1     = (const float*)d_in[4];
    const float* w2     = (const float*)d_in[5];
    const float* b2     = (const float*)d_in[6];
    float* out = (float*)d_out;
    char* ws = (char*)d_ws;

    // ---- workspace layout (~189 MB) ----
    int*   t1_e       = (int*)(ws + 0);
    int*   t1_rs      = (int*)(ws + 512);
    int*   t1_rows    = (int*)(ws + 1024);
    int*   topk_idx   = (int*)(ws + 4096);
    float* topk_prob  = (float*)(ws + 4096 + 65536);
    int*   row_token  = (int*)(ws + 4096 + 2 * 65536);
    float* row_prob   = (float*)(ws + 4096 + 3 * 65536);
    int*   tok2row    = (int*)(ws + 4096 + 4 * 65536);
    int*   block_hist = (int*)(ws + 4096 + 5 * 65536);
    int*   block_base = (int*)(ws + 4096 + 5 * 65536 + 2048);
    size_t off = 1 << 20;
    u16* xb  = (u16*)(ws + off);  off += (size_t)N_TOK * C_DIM * 2;          // 12.58 MB
    u16* w1t = (u16*)(ws + off);  off += (size_t)E_NUM * C_DIM * H_DIM * 2;  // 37.75 MB
    u16* w2t = (u16*)(ws + off);  off += (size_t)E_NUM * C_DIM * H_DIM * 2;  // 37.75 MB
    u16* hbuf= (u16*)(ws + off);                                             // 100.7 MB
    // eo partials [KSPLIT=2][NROWS][C] bf16 = 50.33 MB: overlays xb+w1t exactly
    // (both dead once gemm1 completes; gemm2/combine are stream-ordered after).
    u16* eo  = (u16*)(ws + (1 << 20));

    transpose_cast_kernel<<<dim3(H_DIM / 64, C_DIM / 64, E_NUM), 256, 0, stream>>>(w1, w1t, C_DIM, H_DIM);
    transpose_cast_kernel<<<dim3(C_DIM / 64, H_DIM / 64, E_NUM), 256, 0, stream>>>(w2, w2t, H_DIM, C_DIM);
    gating_kernel<<<N_TOK, 64, 0, stream>>>(x, gate_w, gate_b, topk_idx, topk_prob, xb);
    hist_kernel<<<NBLK, 256, 0, stream>>>(topk_idx, block_hist);
    scan_tables_kernel<<<1, 1, 0, stream>>>(block_hist, t1_e, t1_rs, t1_rows, block_base);
    scatter_kernel<<<NBLK, 256, 0, stream>>>(topk_idx, topk_prob, block_base, row_token, row_prob, tok2row);
    gemm1_kernel<<<NWG1, 512, 0, stream>>>(xb, w1t, b1, t1_e, t1_rs, t1_rows,
                                           row_token, row_prob, hbuf);
    gemm2_kernel<<<NWG2, 512, 0, stream>>>(hbuf, w2t, t1_e, t1_rs, t1_rows, eo);
    combine_kernel<<<N_TOK, 192, 0, stream>>>(eo, tok2row, topk_idx, topk_prob, b2, out);
}

// Round 5
// 464.269 us; speedup vs baseline: 2.3925x; 2.3925x over previous
//
#include <hip/hip_runtime.h>
#include <hip/hip_bf16.h>
#include <math.h>

// ---------------- problem constants ----------------
#define N_TOK 8192          // B*T
#define C_DIM 768
#define E_NUM 8
#define H_DIM 3072
#define NROWS (N_TOK * 2)   // token-expert pairs = 16384
#define MAXT1 72            // row tiles of 256: 16384/256 + 8
#define NBLK  64            // routing blocks (NROWS/256)
#define JN1   24            // gemm1 H col tiles (3072/128)
#define KSPLIT 2
#define KCHUNK (H_DIM / KSPLIT)   // 1536
#define NT1 (C_DIM / 32)          // 24 K-steps gemm1 (divisible by 3)
#define NT2 (KCHUNK / 32)         // 48 K-steps gemm2 (divisible by 3)

typedef unsigned short u16;
typedef __attribute__((ext_vector_type(8))) short   short8;
typedef __attribute__((ext_vector_type(8))) __bf16  bf16x8;
typedef __attribute__((ext_vector_type(4))) float   f32x4;

__device__ __forceinline__ u16 f2bf(float f) {
    __hip_bfloat16 b = __float2bfloat16(f);
    return __builtin_bit_cast(u16, b);
}
__device__ __forceinline__ float bf2f(u16 u) {
    unsigned int v = ((unsigned int)u) << 16;
    return __builtin_bit_cast(float, v);
}

// tanh-form gelu (~3e-4 max dev vs exact, invisible under bf16 noise)
__device__ __forceinline__ float gelu_fast(float x) {
    float x2 = x * x;
    float u  = x * (0.7978845608f + 0.0356774081f * x2);
    float e  = __builtin_amdgcn_exp2f(u * 2.885390082f);     // e^(2u)
    float t  = 1.f - 2.f * __builtin_amdgcn_rcpf(e + 1.f);   // tanh(u)
    return 0.5f * x * (1.f + t);
}

// async global->LDS DMA, 16B per lane; LDS dest is wave-uniform base + lane*16
__device__ __forceinline__ void async_copy16(void* lds, const void* g) {
    __builtin_amdgcn_global_load_lds(
        (const __attribute__((address_space(1))) void*)g,
        (__attribute__((address_space(3))) void*)lds, 16, 0, 0);
}

// ---------------- gating + x cast fused: 1 wave per token ----------------
__global__ void gating_kernel(const float* __restrict__ x, const float* __restrict__ gw,
                              const float* __restrict__ gb,
                              int* __restrict__ topk_idx, float* __restrict__ topk_prob,
                              u16* __restrict__ xb) {
    int token = blockIdx.x;
    int lane  = threadIdx.x;
    const float* xr = x + (size_t)token * C_DIM;
    u16* xbr = xb + (size_t)token * C_DIM;
    float acc[E_NUM];
#pragma unroll
    for (int e = 0; e < E_NUM; ++e) acc[e] = 0.f;
    for (int c = lane; c < C_DIM; c += 64) {
        float xv = xr[c];
        xbr[c] = f2bf(xv);
#pragma unroll
        for (int e = 0; e < E_NUM; ++e) acc[e] += xv * gw[c * E_NUM + e];
    }
#pragma unroll
    for (int e = 0; e < E_NUM; ++e) {
        float v = acc[e];
        for (int off = 32; off > 0; off >>= 1) v += __shfl_down(v, off);
        acc[e] = v;
    }
    if (lane == 0) {
        float l[E_NUM];
#pragma unroll
        for (int e = 0; e < E_NUM; ++e) l[e] = acc[e] + gb[e];
        int e0 = 0;
#pragma unroll
        for (int e = 1; e < E_NUM; ++e) if (l[e] > l[e0]) e0 = e;   // first-index ties like lax.top_k
        int e1 = -1;
#pragma unroll
        for (int e = 0; e < E_NUM; ++e) if (e != e0 && (e1 < 0 || l[e] > l[e1])) e1 = e;
        float p0 = 1.f / (1.f + expf(l[e1] - l[e0]));
        topk_idx[token * 2]      = e0;
        topk_idx[token * 2 + 1]  = e1;
        topk_prob[token * 2]     = p0;
        topk_prob[token * 2 + 1] = 1.f - p0;
    }
}

// ---------------- routing: ballot histogram -> scan -> rank scatter ----------------
__global__ void hist_kernel(const int* __restrict__ topk_idx, int* __restrict__ block_hist) {
    __shared__ int cnt[E_NUM];
    int tid = threadIdx.x;
    if (tid < E_NUM) cnt[tid] = 0;
    __syncthreads();
    int e = topk_idx[blockIdx.x * 256 + tid];
    int lane = tid & 63;
#pragma unroll
    for (int E = 0; E < E_NUM; ++E) {
        unsigned long long m = __ballot(e == E);
        if (lane == 0) atomicAdd(&cnt[E], __popcll(m));   // LDS atomic, 4 waves only
    }
    __syncthreads();
    if (tid < E_NUM) block_hist[blockIdx.x * E_NUM + tid] = cnt[tid];
}

__global__ void scan_tables_kernel(const int* __restrict__ block_hist,
                                   int* __restrict__ t1_e, int* __restrict__ t1_rs, int* __restrict__ t1_rows,
                                   int* __restrict__ block_base) {
    if (threadIdx.x || blockIdx.x) return;
    int counts[E_NUM], offsets[E_NUM];
    for (int e = 0; e < E_NUM; ++e) {
        int s = 0;
        for (int b = 0; b < NBLK; ++b) s += block_hist[b * E_NUM + e];
        counts[e] = s;
    }
    int off = 0;
    for (int e = 0; e < E_NUM; ++e) { offsets[e] = off; off += counts[e]; }
    for (int e = 0; e < E_NUM; ++e) {
        int s = offsets[e];
        for (int b = 0; b < NBLK; ++b) { block_base[b * E_NUM + e] = s; s += block_hist[b * E_NUM + e]; }
    }
    int t = 0;
    for (int e = 0; e < E_NUM; ++e)
        for (int j = 0; j < counts[e]; j += 256) {
            t1_e[t] = e; t1_rs[t] = offsets[e] + j;
            t1_rows[t] = (counts[e] - j < 256) ? (counts[e] - j) : 256;
            ++t;
        }
    for (; t < MAXT1; ++t) { t1_e[t] = 0; t1_rs[t] = 0; t1_rows[t] = 0; }
}

__global__ void scatter_kernel(const int* __restrict__ topk_idx, const float* __restrict__ topk_prob,
                               const int* __restrict__ block_base,
                               int* __restrict__ row_token, float* __restrict__ row_prob,
                               int* __restrict__ tok2row) {
    __shared__ int wcount[4][E_NUM];
    __shared__ int wbase[4][E_NUM];
    int tid = threadIdx.x, lane = tid & 63, wave = tid >> 6;
    int idx = blockIdx.x * 256 + tid;
    int e = topk_idx[idx];
    float p = topk_prob[idx];
    int rank = 0;
    unsigned long long lt = (1ull << lane) - 1ull;
#pragma unroll
    for (int E = 0; E < E_NUM; ++E) {
        unsigned long long m = __ballot(e == E);
        if (lane == 0) wcount[wave][E] = __popcll(m);
        if (e == E) rank = __popcll(m & lt);
    }
    __syncthreads();
    if (tid < E_NUM) {
        int s = 0;
#pragma unroll
        for (int w = 0; w < 4; ++w) { wbase[w][tid] = s; s += wcount[w][tid]; }
    }
    __syncthreads();
    int pos = block_base[blockIdx.x * E_NUM + e] + wbase[wave][e] + rank;
    row_token[pos] = idx >> 1;
    row_prob[pos]  = p;
    tok2row[idx]   = pos;
}

// in: [E][R][C] fp32 -> out: [E][C][R] bf16.  64x64 tile, 256 threads.
__global__ void transpose_cast_kernel(const float* __restrict__ in, u16* __restrict__ out,
                                      int R, int C) {
    __shared__ float tile[64][65];
    size_t mat = (size_t)R * C;
    const float* src = in + blockIdx.z * mat;
    u16* dst = out + blockIdx.z * mat;
    int c0 = blockIdx.x * 64, r0 = blockIdx.y * 64;
    int tx = threadIdx.x & 15, ty = threadIdx.x >> 4;   // 16 x 16
#pragma unroll
    for (int k = 0; k < 4; ++k) {
        float4 v = *(const float4*)(src + (size_t)(r0 + ty + 16 * k) * C + c0 + tx * 4);
        tile[ty + 16 * k][tx * 4 + 0] = v.x;
        tile[ty + 16 * k][tx * 4 + 1] = v.y;
        tile[ty + 16 * k][tx * 4 + 2] = v.z;
        tile[ty + 16 * k][tx * 4 + 3] = v.w;
    }
    __syncthreads();
#pragma unroll
    for (int k = 0; k < 4; ++k) {
        int c = ty + 16 * k;
        u16 p[4];
#pragma unroll
        for (int j = 0; j < 4; ++j) p[j] = f2bf(tile[tx * 4 + j][c]);
        *(unsigned long long*)(dst + (size_t)(c0 + c) * R + r0 + tx * 4) =
            *(unsigned long long*)p;
    }
}

// ============ GEMM cores: 256x128 tile, BK=32, TRIPLE-buffered 72KB LDS ============
// R3's proven machinery (asm ds_read + counted vmcnt; passed, VGPR 56, 0 conflicts)
// with prefetch distance extended 1 -> 2 bodies. Per body t (reads buf t%3):
//   STAGE(t+2) -> buf[(t+2)%3] (3 DMA insts); s_waitcnt vmcnt(6)  <- retires
//   exactly STAGE(t), issued TWO bodies ago (~1200 cy cover vs HBM ~900);
//   s_barrier; inline-asm ds_read_b128 x8; lgkmcnt(0); sched_barrier(0);
//   16 MFMA in setprio(1); s_barrier.
// Tail ledger: body NT-2 -> vmcnt(3); body NT-1 -> vmcnt(0).
// Overwrite safety: buf[(t+2)%3] holds tile t-1, whose readers all passed body
// t-1's closing barrier before any wave enters body t. LDS = 3*(16+8) KB = 72 KB
// -> 2 blocks/CU (16 waves/CU keeps inter-block overlap on top of the pipeline).
// LDS layout (R3-verified): 128B lines = 2 rows x 4 k-chunks of 16B, phys unit
// ((r&1)*4 + kc) ^ (line&7); DMA sources pre-swizzled with the exact inverse.

#define SP1 __builtin_amdgcn_s_setprio(1)
#define SP0 __builtin_amdgcn_s_setprio(0)
#define BAR() __builtin_amdgcn_s_barrier()
#define SCB0 __builtin_amdgcn_sched_barrier(0)
#define VMCNT(n) asm volatile("s_waitcnt vmcnt(" #n ")" ::: "memory")
#define LGKM0 asm volatile("s_waitcnt lgkmcnt(0)" ::: "memory")

#define DSR(dst, addr, OFF) \
    asm volatile("ds_read_b128 %0, %1 offset:" #OFF : "=v"(dst) : "v"(addr))

#define STAGE3(BUF, s) do { \
    async_copy16(&As[BUF][(size_t)tid * 8],         a_src0 + (s) * 32); \
    async_copy16(&As[BUF][(size_t)(512 + tid) * 8], a_src1 + (s) * 32); \
    async_copy16(&Bs[BUF][(size_t)tid * 8],         b_src0 + (s) * 32); } while (0)

#define BODY3(t, BUF, NT) do { \
    if ((t) + 2 < (NT)) { STAGE3((((BUF) + 2) % 3), (t) + 2); VMCNT(6); } \
    else if ((t) + 1 < (NT)) { VMCNT(3); } \
    else { VMCNT(0); } \
    BAR(); \
    f32x4 av[4], bv[4]; \
    { \
        unsigned pa = aslds + (BUF) * 16384 + paoff; \
        unsigned pb = bslds + (BUF) * 8192  + pboff; \
        DSR(av[0], pa, 0); DSR(av[1], pa, 1024); DSR(av[2], pa, 2048); DSR(av[3], pa, 3072); \
        DSR(bv[0], pb, 0); DSR(bv[1], pb, 1024); DSR(bv[2], pb, 2048); DSR(bv[3], pb, 3072); \
    } \
    LGKM0; SCB0; SP1; \
    _Pragma("unroll") \
    for (int i = 0; i < 4; ++i) { \
        bf16x8 afr = __builtin_bit_cast(bf16x8, av[i]); \
        _Pragma("unroll") \
        for (int j = 0; j < 4; ++j) \
            acc[i][j] = __builtin_amdgcn_mfma_f32_16x16x32_bf16( \
                afr, __builtin_bit_cast(bf16x8, bv[j]), acc[i][j], 0, 0, 0); \
    } \
    SP0; \
    BAR(); \
} while (0)

#define GEMM_LOOP(NT) do { \
    STAGE3(0, 0); \
    STAGE3(1, 1); \
    _Pragma("unroll 1") \
    for (int t = 0; t < (NT); t += 3) { \
        BODY3(t,     0, NT); \
        BODY3(t + 1, 1, NT); \
        BODY3(t + 2, 2, NT); \
    } \
} while (0)

// ---------------- GEMM1: h[r,:] = row_prob[r] * gelu(Xg[r,:] @ W1[e] + b1[e]) ----------------
__global__ __launch_bounds__(512) void gemm1_kernel(
    const u16* __restrict__ xb,     // [N_TOK][C]
    const u16* __restrict__ w1t,    // [E][H][C]
    const float* __restrict__ b1,   // [E][H]
    const int* __restrict__ tile_e, const int* __restrict__ tile_rs,
    const int* __restrict__ tile_nrows,
    const int* __restrict__ row_token, const float* __restrict__ row_prob,
    u16* __restrict__ h)            // [NROWS][H]
{
    // A-reuse swizzle: all XCDs sweep the same bt together (xb row-tile served
    // once via L3); each XCD's 3 jn blocks back-to-back reuse the A-tile in L2.
    const int l = blockIdx.x;
    const int xc = l & 7, s = l >> 3;     // s in [0, 216)
    const int bt = s / 3;                 // [0, 72)
    const int jn = xc + 8 * (s % 3);      // [0, 24)

    const int rows = tile_nrows[bt];
    if (rows == 0) return;
    const int e = tile_e[bt];
    const int row_start = tile_rs[bt];

    __shared__ __align__(16) u16 As[3][8192];   // 3 x 16 KB
    __shared__ __align__(16) u16 Bs[3][4096];   // 3 x 8 KB

    const int tid = threadIdx.x;
    const int lane = tid & 63;
    const int wave = tid >> 6;
    const int wm = wave & 3, wn = wave >> 2;
    const int m_in = lane & 15, quad = lane >> 4;

    // DMA sources, pre-swizzled inverse of the LDS layout
    const u16* a_src0; const u16* a_src1; const u16* b_src0;
    {
        int d0 = tid,        ln0 = d0 >> 3, ul0 = (d0 & 7) ^ (ln0 & 7);
        int r0 = 2 * ln0 + (ul0 >> 2), kc0 = ul0 & 3;
        int d1 = 512 + tid,  ln1 = d1 >> 3, ul1 = (d1 & 7) ^ (ln1 & 7);
        int r1 = 2 * ln1 + (ul1 >> 2), kc1 = ul1 & 3;
        int tok0 = row_token[row_start + ((r0 < rows) ? r0 : 0)];
        int tok1 = row_token[row_start + ((r1 < rows) ? r1 : 0)];
        a_src0 = xb + (size_t)tok0 * C_DIM + kc0 * 8;
        a_src1 = xb + (size_t)tok1 * C_DIM + kc1 * 8;
        b_src0 = w1t + ((size_t)e * H_DIM + jn * 128 + r0) * C_DIM + kc0 * 8;
    }

    // fragment LDS byte addresses
    const unsigned phys  = ((((unsigned)m_in & 1) * 4 + quad) ^ (((unsigned)m_in >> 1) & 7)) * 16;
    const unsigned paoff = (unsigned)(wm * 32 + (m_in >> 1)) * 128 + phys;
    const unsigned pboff = (unsigned)(wn * 32 + (m_in >> 1)) * 128 + phys;
    const unsigned aslds = (unsigned)(size_t)&As[0][0];
    const unsigned bslds = (unsigned)(size_t)&Bs[0][0];

    f32x4 acc[4][4];
#pragma unroll
    for (int i = 0; i < 4; ++i)
#pragma unroll
        for (int j = 0; j < 4; ++j) acc[i][j] = (f32x4){0.f, 0.f, 0.f, 0.f};

    GEMM_LOOP(NT1);

    const float* b1e = b1 + e * H_DIM + jn * 128;
#pragma unroll
    for (int i = 0; i < 4; ++i) {
#pragma unroll
        for (int r = 0; r < 4; ++r) {
            int lrow = wm * 64 + i * 16 + quad * 4 + r;
            if (lrow < rows) {
                int grow = row_start + lrow;
                float p = row_prob[grow];
#pragma unroll
                for (int j = 0; j < 4; ++j) {
                    int lcol = wn * 64 + j * 16 + m_in;
                    float v = acc[i][j][r] + b1e[lcol];
                    h[(size_t)grow * H_DIM + jn * 128 + lcol] = f2bf(gelu_fast(v) * p);
                }
            }
        }
    }
}

// ---------------- GEMM2: 256x128 tile, split-K=2, bf16 partials ----------------
__global__ __launch_bounds__(512) void gemm2_kernel(
    const u16* __restrict__ hin,    // [NROWS][H]
    const u16* __restrict__ w2t,    // [E][C][H]
    const int* __restrict__ tile_e, const int* __restrict__ tile_rs,
    const int* __restrict__ tile_nrows,
    u16* __restrict__ eo)           // [KSPLIT][NROWS][C] bf16 partials
{
    // XCD swizzle (R0-verified): combo fastest within XCD (A-tile L2 reuse)
    const int l = blockIdx.x;
    const int xc = l & 7, s = l >> 3;     // s in [0, 108)
    const int combo = s % 12;
    const int bt = xc + 8 * (s / 12);     // [0, 72)
    const int jn = combo >> 1;            // [0, 6)
    const int kz = combo & 1;

    const int rows = tile_nrows[bt];
    if (rows == 0) return;
    const int e = tile_e[bt];
    const int row_start = tile_rs[bt];

    __shared__ __align__(16) u16 As[3][8192];
    __shared__ __align__(16) u16 Bs[3][4096];

    const int tid = threadIdx.x;
    const int lane = tid & 63;
    const int wave = tid >> 6;
    const int wm = wave & 3, wn = wave >> 2;
    const int m_in = lane & 15, quad = lane >> 4;

    const u16* a_src0; const u16* a_src1; const u16* b_src0;
    {
        int d0 = tid,        ln0 = d0 >> 3, ul0 = (d0 & 7) ^ (ln0 & 7);
        int r0 = 2 * ln0 + (ul0 >> 2), kc0 = ul0 & 3;
        int d1 = 512 + tid,  ln1 = d1 >> 3, ul1 = (d1 & 7) ^ (ln1 & 7);
        int r1 = 2 * ln1 + (ul1 >> 2), kc1 = ul1 & 3;
        int ar0 = (r0 < rows) ? r0 : 0;
        int ar1 = (r1 < rows) ? r1 : 0;
        a_src0 = hin + (size_t)(row_start + ar0) * H_DIM + kz * KCHUNK + kc0 * 8;
        a_src1 = hin + (size_t)(row_start + ar1) * H_DIM + kz * KCHUNK + kc1 * 8;
        b_src0 = w2t + ((size_t)e * C_DIM + jn * 128 + r0) * H_DIM + kz * KCHUNK + kc0 * 8;
    }

    const unsigned phys  = ((((unsigned)m_in & 1) * 4 + quad) ^ (((unsigned)m_in >> 1) & 7)) * 16;
    const unsigned paoff = (unsigned)(wm * 32 + (m_in >> 1)) * 128 + phys;
    const unsigned pboff = (unsigned)(wn * 32 + (m_in >> 1)) * 128 + phys;
    const unsigned aslds = (unsigned)(size_t)&As[0][0];
    const unsigned bslds = (unsigned)(size_t)&Bs[0][0];

    f32x4 acc[4][4];
#pragma unroll
    for (int i = 0; i < 4; ++i)
#pragma unroll
        for (int j = 0; j < 4; ++j) acc[i][j] = (f32x4){0.f, 0.f, 0.f, 0.f};

    GEMM_LOOP(NT2);

    u16* eop = eo + (size_t)kz * NROWS * C_DIM;
#pragma unroll
    for (int i = 0; i < 4; ++i) {
#pragma unroll
        for (int r = 0; r < 4; ++r) {
            int lrow = wm * 64 + i * 16 + quad * 4 + r;
            if (lrow < rows) {
                u16* orow = eop + (size_t)(row_start + lrow) * C_DIM + jn * 128;
#pragma unroll
                for (int j = 0; j < 4; ++j)
                    orow[wn * 64 + j * 16 + m_in] = f2bf(acc[i][j][r]);
            }
        }
    }
}

// ---------------- combine: out[t] = sum of 4 partial rows + weighted biases ----------------
__global__ void combine_kernel(const u16* __restrict__ eo, const int* __restrict__ tok2row,
                               const int* __restrict__ topk_idx, const float* __restrict__ topk_prob,
                               const float* __restrict__ b2, float* __restrict__ out) {
    int t = blockIdx.x;
    int c = threadIdx.x * 4;                      // 192 threads x 4 floats = 768
    int r0 = tok2row[t * 2], r1 = tok2row[t * 2 + 1];
    int e0 = topk_idx[t * 2], e1 = topk_idx[t * 2 + 1];
    float p0 = topk_prob[t * 2], p1 = topk_prob[t * 2 + 1];
    const u16* a0 = eo + (size_t)r0 * C_DIM + c;
    const u16* a1 = eo + (size_t)NROWS * C_DIM + (size_t)r0 * C_DIM + c;
    const u16* b0 = eo + (size_t)r1 * C_DIM + c;
    const u16* b1 = eo + (size_t)NROWS * C_DIM + (size_t)r1 * C_DIM + c;
    ushort4 va0 = *(const ushort4*)a0, va1 = *(const ushort4*)a1;
    ushort4 vb0 = *(const ushort4*)b0, vb1 = *(const ushort4*)b1;
    float4 g0 = *(const float4*)(b2 + e0 * C_DIM + c);
    float4 g1 = *(const float4*)(b2 + e1 * C_DIM + c);
    float4 o;
    o.x = bf2f(va0.x) + bf2f(va1.x) + bf2f(vb0.x) + bf2f(vb1.x) + p0 * g0.x + p1 * g1.x;
    o.y = bf2f(va0.y) + bf2f(va1.y) + bf2f(vb0.y) + bf2f(vb1.y) + p0 * g0.y + p1 * g1.y;
    o.z = bf2f(va0.z) + bf2f(va1.z) + bf2f(vb0.z) + bf2f(vb1.z) + p0 * g0.z + p1 * g1.z;
    o.w = bf2f(va0.w) + bf2f(va1.w) + bf2f(vb0.w) + bf2f(vb1.w) + p0 * g0.w + p1 * g1.w;
    *(float4*)(out + (size_t)t * C_DIM + c) = o;
}

// ---------------- launch ----------------
extern "C" void kernel_launch(void* const* d_in, const int* in_sizes, int n_in,
                              void* d_out, int out_size, void* d_ws, size_t ws_size,
                              hipStream_t stream) {
    const float* x      = (const float*)d_in[0];
    const float* gate_w = (const float*)d_in[1];
    const float* gate_b = (const float*)d_in[2];
    const float* w1     = (const float*)d_in[3];
    const float* b1     = (const float*)d_in[4];
    const float* w2     = (const float*)d_in[5];
    const float* b2     = (const float*)d_in[6];
    float* out = (float*)d_out;
    char* ws = (char*)d_ws;

    // ---- workspace layout (~189 MB) ----
    int*   t1_e       = (int*)(ws + 0);
    int*   t1_rs      = (int*)(ws + 512);
    int*   t1_rows    = (int*)(ws + 1024);
    int*   topk_idx   = (int*)(ws + 4096);
    float* topk_prob  = (float*)(ws + 4096 + 65536);
    int*   row_token  = (int*)(ws + 4096 + 2 * 65536);
    float* row_prob   = (float*)(ws + 4096 + 3 * 65536);
    int*   tok2row    = (int*)(ws + 4096 + 4 * 65536);
    int*   block_hist = (int*)(ws + 4096 + 5 * 65536);
    int*   block_base = (int*)(ws + 4096 + 5 * 65536 + 2048);
    size_t off = 1 << 20;
    u16* xb  = (u16*)(ws + off);  off += (size_t)N_TOK * C_DIM * 2;          // 12.58 MB
    u16* w1t = (u16*)(ws + off);  off += (size_t)E_NUM * C_DIM * H_DIM * 2;  // 37.75 MB
    u16* w2t = (u16*)(ws + off);  off += (size_t)E_NUM * C_DIM * H_DIM * 2;  // 37.75 MB
    u16* hbuf= (u16*)(ws + off);                                             // 100.7 MB
    // eo partials [KSPLIT=2][NROWS][C] bf16 = 50.33 MB: overlays xb+w1t exactly
    // (both dead once gemm1 completes; gemm2/combine are stream-ordered after).
    u16* eo  = (u16*)(ws + (1 << 20));

    transpose_cast_kernel<<<dim3(H_DIM / 64, C_DIM / 64, E_NUM), 256, 0, stream>>>(w1, w1t, C_DIM, H_DIM);
    transpose_cast_kernel<<<dim3(C_DIM / 64, H_DIM / 64, E_NUM), 256, 0, stream>>>(w2, w2t, H_DIM, C_DIM);
    gating_kernel<<<N_TOK, 64, 0, stream>>>(x, gate_w, gate_b, topk_idx, topk_prob, xb);
    hist_kernel<<<NBLK, 256, 0, stream>>>(topk_idx, block_hist);
    scan_tables_kernel<<<1, 1, 0, stream>>>(block_hist, t1_e, t1_rs, t1_rows, block_base);
    scatter_kernel<<<NBLK, 256, 0, stream>>>(topk_idx, topk_prob, block_base, row_token, row_prob, tok2row);
    gemm1_kernel<<<MAXT1 * JN1, 512, 0, stream>>>(xb, w1t, b1, t1_e, t1_rs, t1_rows,
                                                  row_token, row_prob, hbuf);
    gemm2_kernel<<<MAXT1 * 6 * KSPLIT, 512, 0, stream>>>(hbuf, w2t, t1_e, t1_rs, t1_rows, eo);
    combine_kernel<<<N_TOK, 192, 0, stream>>>(eo, tok2row, topk_idx, topk_prob, b2, out);
}